// Round 9
// baseline (1547.667 us; speedup 1.0000x reference)
//
#include <hip/hip_runtime.h>

typedef unsigned short u16;
typedef unsigned int   u32;
typedef _Float16       f16;

#define B_SZ 2048
#define S_SZ 1024
#define N3   3072
#define F_SZ 50

typedef f16    f16x8 __attribute__((ext_vector_type(8)));
typedef f16    f16x4 __attribute__((ext_vector_type(4)));
typedef float  f32x4 __attribute__((ext_vector_type(4)));
typedef u32    u32x4 __attribute__((ext_vector_type(4)));

// async global->LDS, 16B per lane; LDS dest = base + lane*16 (wave-uniform base)
__device__ __forceinline__ void glds16(const void* g, void* l) {
    __builtin_amdgcn_global_load_lds(
        (const __attribute__((address_space(1))) u32*)g,
        (__attribute__((address_space(3))) u32*)l, 16, 0, 0);
}

// ---------------------------------------------------------------------------
// Mx[2][3072] = W_emb @ W_gru[0:1024, :]  (split-K + atomics; Mx pre-zeroed)
__global__ __launch_bounds__(256) void make_mx(
    const float* __restrict__ We, const float* __restrict__ Wg,
    float* __restrict__ Mx)
{
    int j  = blockIdx.x * 256 + threadIdx.x;
    int k0 = blockIdx.y * 64;
    float s0 = 0.f, s1 = 0.f;
    #pragma unroll 4
    for (int k = k0; k < k0 + 64; k++) {
        float w = Wg[(size_t)k * N3 + j];
        s0 += We[k] * w;
        s1 += We[S_SZ + k] * w;
    }
    atomicAdd(&Mx[j], s0);
    atomicAdd(&Mx[N3 + j], s1);
}

// ---------------------------------------------------------------------------
// Wt[n][k] = fp16(W_gru[1024+k][n])
__global__ __launch_bounds__(256) void transpose_w(
    const float* __restrict__ Wg, f16* __restrict__ Wt)
{
    __shared__ float tile[32][33];
    int n0 = blockIdx.x * 32, k0 = blockIdx.y * 32;
    int c = threadIdx.x & 31, r = threadIdx.x >> 5;
    #pragma unroll
    for (int s = 0; s < 4; s++) {
        int rr = r + s * 8;
        tile[rr][c] = Wg[(size_t)(S_SZ + k0 + rr) * N3 + n0 + c];
    }
    __syncthreads();
    #pragma unroll
    for (int s = 0; s < 4; s++) {
        int rr = r + s * 8;
        Wt[(size_t)(n0 + rr) * S_SZ + k0 + c] = (f16)tile[c][rr];
    }
}

// ---------------------------------------------------------------------------
// 64x128 tile, BK=64, glds16 staging, XOR-swizzled unpadded LDS.
// Grid dim3(24, 32): bx = N-tile, by = M-tile. Linear block id = bx + 24*by
// == bx (mod 8), so each XCD sees only 3 N-slices of Wt (768 KB) ->
// L2-resident across the dispatch AND across steps. (R8's dim3(32,24) made
// every XCD stream all 6 MB of Wt per step from L3.)
__global__ __launch_bounds__(256) void gemm_step(
    const f16* __restrict__ Wt,    // [3072][1024] fp16
    const f16* __restrict__ hh,    // [2048][1024] fp16 state
    const float* __restrict__ Mx,  // [2][3072]
    const float* __restrict__ act, // [2048][50][2]
    f16* __restrict__ parts,       // [2048][3072] f16
    int t)
{
    __shared__ __align__(16) f16 As[64 * 64];    // 8 KB
    __shared__ __align__(16) f16 Bs[128 * 64];   // 16 KB
    const int n0 = blockIdx.x * 128;
    const int m0 = blockIdx.y * 64;
    const int tid  = threadIdx.x;
    const int lane = tid & 63;
    const int wave = tid >> 6;
    const int wr = (wave >> 1) * 32;   // wave row offset (A)
    const int wc = (wave & 1) * 64;    // wave col offset (B)
    const int quad = lane >> 4, lrow = lane & 15;
    const int swz = (lrow & 7) * 8;

    // staging lane geometry: 8 rows x 64 halves per 1KB chunk
    const int lrow8 = lane >> 3;
    const int scolh = ((lane & 7) * 8) ^ (lrow8 * 8);  // swizzled source col

    // preload epilogue rank-2 columns (removes end-of-block load latency)
    float mx0[4], mx1[4];
    #pragma unroll
    for (int j = 0; j < 4; j++) {
        int n = n0 + wc + j * 16 + lrow;
        mx0[j] = Mx[n]; mx1[j] = Mx[N3 + n];
    }

    f32x4 acc[2][4];
    #pragma unroll
    for (int i = 0; i < 2; i++)
        #pragma unroll
        for (int j = 0; j < 4; j++)
            acc[i][j] = (f32x4){0.f, 0.f, 0.f, 0.f};

    for (int kb = 0; kb < S_SZ; kb += 64) {
        __syncthreads();
        #pragma unroll
        for (int c = 0; c < 2; c++) {          // A: 8 chunks, 2 per wave
            int ch = wave * 2 + c;
            int row = ch * 8 + lrow8;
            glds16(&hh[(size_t)(m0 + row) * S_SZ + kb + scolh], &As[ch * 512]);
        }
        #pragma unroll
        for (int c = 0; c < 4; c++) {          // B: 16 chunks, 4 per wave
            int ch = wave * 4 + c;
            int row = ch * 8 + lrow8;
            glds16(&Wt[(size_t)(n0 + row) * S_SZ + kb + scolh], &Bs[ch * 512]);
        }
        __syncthreads();
        #pragma unroll
        for (int kk = 0; kk < 64; kk += 32) {
            f16x8 a[2], b[4];
            #pragma unroll
            for (int i = 0; i < 2; i++)
                a[i] = __builtin_bit_cast(f16x8,
                    *(const u32x4*)&As[(wr + i * 16 + lrow) * 64 +
                                       ((kk + quad * 8) ^ swz)]);
            #pragma unroll
            for (int j = 0; j < 4; j++)
                b[j] = __builtin_bit_cast(f16x8,
                    *(const u32x4*)&Bs[(wc + j * 16 + lrow) * 64 +
                                       ((kk + quad * 8) ^ swz)]);
            #pragma unroll
            for (int i = 0; i < 2; i++)
                #pragma unroll
                for (int j = 0; j < 4; j++)
                    acc[i][j] = __builtin_amdgcn_mfma_f32_16x16x32_f16(
                        a[i], b[j], acc[i][j], 0, 0, 0);
        }
    }

    #pragma unroll
    for (int i = 0; i < 2; i++) {
        #pragma unroll
        for (int rr = 0; rr < 4; rr++) {
            int m = m0 + wr + i * 16 + quad * 4 + rr;
            float a0 = act[((size_t)m * F_SZ + t) * 2 + 0];
            float a1 = act[((size_t)m * F_SZ + t) * 2 + 1];
            #pragma unroll
            for (int j = 0; j < 4; j++) {
                int n = n0 + wc + j * 16 + lrow;
                parts[(size_t)m * N3 + n] =
                    (f16)(acc[i][j][rr] + a0 * mx0[j] + a1 * mx1[j]);
            }
        }
    }
}

// ---------------------------------------------------------------------------
// LayerNorm + gates + h update. 2 rows/block; thread owns 8 units.
// h state fp16-only during recurrence; fp32 h written to d_out at t=49.
__global__ __launch_bounds__(256) void ln_gate_step(
    const f16* __restrict__ parts,
    const float* __restrict__ gamma,
    const float* __restrict__ beta,
    f16* __restrict__ hh,           // fp16 state
    float* __restrict__ hout,       // d_out h region (written only at t=49)
    int t)
{
    const int tid = threadIdx.x;
    const int r2  = tid >> 7;                 // 0..1
    const int tl  = tid & 127;                // owns units tl*8..tl*8+7
    const int row = blockIdx.x * 2 + r2;
    const f16* p = parts + (size_t)row * N3 + tl * 8;

    float v[24];
    float s = 0.f, ss = 0.f;
    #pragma unroll
    for (int g = 0; g < 3; g++) {
        f16x8 x = *(const f16x8*)(p + g * S_SZ);
        #pragma unroll
        for (int e = 0; e < 8; e++) {
            float f = (float)x[e];
            v[g * 8 + e] = f;
            s += f; ss += f * f;
        }
    }
    #pragma unroll
    for (int o = 1; o < 64; o <<= 1) {
        s  += __shfl_xor(s, o);
        ss += __shfl_xor(ss, o);
    }
    __shared__ float red[8];
    int wave = tid >> 6, lane = tid & 63;
    if (lane == 0) { red[wave] = s; red[4 + wave] = ss; }
    __syncthreads();
    float S  = red[r2 * 2] + red[r2 * 2 + 1];
    float SS = red[4 + r2 * 2] + red[4 + r2 * 2 + 1];
    float mean = S * (1.f / N3);
    float var  = SS * (1.f / N3) - mean * mean;
    float rstd = rsqrtf(var + 1e-3f);

    float nv[24];
    #pragma unroll
    for (int g = 0; g < 3; g++) {
        f32x4 g0 = *(const f32x4*)(gamma + g * S_SZ + tl * 8);
        f32x4 g1 = *(const f32x4*)(gamma + g * S_SZ + tl * 8 + 4);
        f32x4 b0 = *(const f32x4*)(beta  + g * S_SZ + tl * 8);
        f32x4 b1 = *(const f32x4*)(beta  + g * S_SZ + tl * 8 + 4);
        #pragma unroll
        for (int e = 0; e < 4; e++) {
            nv[g * 8 + e]     = (v[g * 8 + e]     - mean) * rstd * g0[e] + b0[e];
            nv[g * 8 + e + 4] = (v[g * 8 + e + 4] - mean) * rstd * g1[e] + b1[e];
        }
    }

    size_t hbase = (size_t)row * S_SZ + tl * 8;
    f16x8 hp = *(const f16x8*)(hh + hbase);
    f16x8 hs;
    f32x4 ho0, ho1;
    #pragma unroll
    for (int e = 0; e < 8; e++) {
        float rg = 1.f / (1.f + __expf(-nv[e]));
        float x  = rg * nv[8 + e];
        float tt = __expf(-2.f * fabsf(x));            // stable fast tanh
        float cg = __builtin_copysignf((1.f - tt) / (1.f + tt), x);
        float ug = 1.f / (1.f + __expf(-(nv[16 + e] - 1.f)));
        float hv = ug * cg + (1.f - ug) * (float)hp[e];
        hs[e] = (f16)hv;
        if (e < 4) ho0[e] = hv; else ho1[e - 4] = hv;
    }
    *(f16x8*)(hh + hbase) = hs;
    if (t == F_SZ - 1) {
        *(f32x4*)(hout + hbase)     = ho0;
        *(f32x4*)(hout + hbase + 4) = ho1;
    }
}

// ---------------------------------------------------------------------------
// out[B*S + row*2 + {0,1}] = h_row @ W_dec + b_dec   (fp32)
__global__ __launch_bounds__(256) void final_out(
    const float* __restrict__ h, const float* __restrict__ Wd,
    const float* __restrict__ bd, float* __restrict__ out)
{
    int row = blockIdx.x * 4 + (threadIdx.x >> 6);
    int lane = threadIdx.x & 63;
    const float* hr = h + (size_t)row * S_SZ;
    float s0 = 0.f, s1 = 0.f;
    #pragma unroll
    for (int k = lane; k < S_SZ; k += 64) {
        float x = hr[k];
        s0 += x * Wd[k * 2];
        s1 += x * Wd[k * 2 + 1];
    }
    #pragma unroll
    for (int o = 32; o > 0; o >>= 1) {
        s0 += __shfl_down(s0, o);
        s1 += __shfl_down(s1, o);
    }
    if (lane == 0) {
        out[(size_t)B_SZ * S_SZ + row * 2 + 0] = s0 + bd[0];
        out[(size_t)B_SZ * S_SZ + row * 2 + 1] = s1 + bd[1];
    }
}

// ---------------------------------------------------------------------------
extern "C" void kernel_launch(void* const* d_in, const int* in_sizes, int n_in,
                              void* d_out, int out_size, void* d_ws, size_t ws_size,
                              hipStream_t stream)
{
    const float* act = (const float*)d_in[0]; // [2048][50][2]
    const float* We  = (const float*)d_in[1]; // [2][1024]
    const float* Wg  = (const float*)d_in[2]; // [2048][3072]
    const float* lng = (const float*)d_in[3]; // [3072]
    const float* lnb = (const float*)d_in[4]; // [3072]
    const float* Wd  = (const float*)d_in[5]; // [1024][2]
    const float* bd  = (const float*)d_in[6]; // [2]
    float* out = (float*)d_out;               // fp32 [B*S h_last][B*2 outputs]

    char* ws = (char*)d_ws;                   // ws_size = 256 MiB (measured)
    f16*   Wt    = (f16*)ws;                  //  6,291,456 B
    float* Mx    = (float*)(ws + 6291456);    //     24,576 B
    f16*   hh    = (f16*)(ws + 6316032);      //  4,194,304 B fp16 state
    f16*   parts = (f16*)(ws + 10510336);     // 12,582,912 B

    hipMemsetAsync(hh, 0, (size_t)B_SZ * S_SZ * 2, stream);
    hipMemsetAsync(Mx, 0, 2 * N3 * 4, stream);
    make_mx<<<dim3(N3 / 256, 16), 256, 0, stream>>>(We, Wg, Mx);
    transpose_w<<<dim3(N3 / 32, S_SZ / 32), 256, 0, stream>>>(Wg, Wt);

    for (int t = 0; t < F_SZ; t++) {
        gemm_step<<<dim3(24, 32), 256, 0, stream>>>(Wt, hh, Mx, act, parts, t);
        ln_gate_step<<<B_SZ / 2, 256, 0, stream>>>(parts, lng, lnb, hh, out, t);
    }
    final_out<<<B_SZ / 4, 256, 0, stream>>>(out, Wd, bd, out);
}

// Round 10
// 1447.026 us; speedup vs baseline: 1.0696x; 1.0696x over previous
//
#include <hip/hip_runtime.h>

typedef unsigned short u16;
typedef unsigned int   u32;
typedef _Float16       f16;

#define B_SZ 2048
#define S_SZ 1024
#define N3   3072
#define F_SZ 50

typedef f16    f16x8 __attribute__((ext_vector_type(8)));
typedef f16    f16x4 __attribute__((ext_vector_type(4)));
typedef float  f32x4 __attribute__((ext_vector_type(4)));
typedef u32    u32x4 __attribute__((ext_vector_type(4)));

// async global->LDS, 16B per lane; LDS dest = base + lane*16 (wave-uniform base)
__device__ __forceinline__ void glds16(const void* g, void* l) {
    __builtin_amdgcn_global_load_lds(
        (const __attribute__((address_space(1))) u32*)g,
        (__attribute__((address_space(3))) u32*)l, 16, 0, 0);
}

// ---------------------------------------------------------------------------
// Mx[2][3072] = W_emb @ W_gru[0:1024, :]  (split-K + atomics; Mx pre-zeroed)
__global__ __launch_bounds__(256) void make_mx(
    const float* __restrict__ We, const float* __restrict__ Wg,
    float* __restrict__ Mx)
{
    int j  = blockIdx.x * 256 + threadIdx.x;
    int k0 = blockIdx.y * 64;
    float s0 = 0.f, s1 = 0.f;
    #pragma unroll 4
    for (int k = k0; k < k0 + 64; k++) {
        float w = Wg[(size_t)k * N3 + j];
        s0 += We[k] * w;
        s1 += We[S_SZ + k] * w;
    }
    atomicAdd(&Mx[j], s0);
    atomicAdd(&Mx[N3 + j], s1);
}

// ---------------------------------------------------------------------------
// Wt[n][k] = fp16(W_gru[1024+k][n])
__global__ __launch_bounds__(256) void transpose_w(
    const float* __restrict__ Wg, f16* __restrict__ Wt)
{
    __shared__ float tile[32][33];
    int n0 = blockIdx.x * 32, k0 = blockIdx.y * 32;
    int c = threadIdx.x & 31, r = threadIdx.x >> 5;
    #pragma unroll
    for (int s = 0; s < 4; s++) {
        int rr = r + s * 8;
        tile[rr][c] = Wg[(size_t)(S_SZ + k0 + rr) * N3 + n0 + c];
    }
    __syncthreads();
    #pragma unroll
    for (int s = 0; s < 4; s++) {
        int rr = r + s * 8;
        Wt[(size_t)(n0 + rr) * S_SZ + k0 + c] = (f16)tile[c][rr];
    }
}

// ---------------------------------------------------------------------------
// 64x128 tile, BK=64, glds16 staging, XOR-swizzled unpadded LDS (R8 core).
// 1-D grid 768; 96-block chunks decode to 16M x 6N rectangles. Under the
// contiguous-chunk XCD model (evidence: R8 vs R9 asymmetry), each XCD's
// working set = hh 2MB + Wt 1.5MB (both L2-resident, Wt persists across
// steps). parts is written non-temporally to avoid evicting them.
__global__ __launch_bounds__(256) void gemm_step(
    const f16* __restrict__ Wt,    // [3072][1024] fp16
    const f16* __restrict__ hh,    // [2048][1024] fp16 state
    const float* __restrict__ Mx,  // [2][3072]
    const float* __restrict__ act, // [2048][50][2]
    f16* __restrict__ parts,       // [2048][3072] f16
    int t)
{
    __shared__ __align__(16) f16 As[64 * 64];    // 8 KB
    __shared__ __align__(16) f16 Bs[128 * 64];   // 16 KB

    const int blk    = blockIdx.x;
    const int chunk  = blk / 96;                 // 0..7  (XCD under contig model)
    const int within = blk % 96;
    const int mt = (chunk & 1) * 16 + (within & 15);    // 0..31
    const int nt = (chunk >> 1) * 6 + (within >> 4);    // 0..23
    const int m0 = mt * 64;
    const int n0 = nt * 128;

    const int tid  = threadIdx.x;
    const int lane = tid & 63;
    const int wave = tid >> 6;
    const int wr = (wave >> 1) * 32;   // wave row offset (A)
    const int wc = (wave & 1) * 64;    // wave col offset (B)
    const int quad = lane >> 4, lrow = lane & 15;
    const int swz = (lrow & 7) * 8;

    // staging lane geometry: 8 rows x 64 halves per 1KB chunk
    const int lrow8 = lane >> 3;
    const int scolh = ((lane & 7) * 8) ^ (lrow8 * 8);  // swizzled source col

    // preload epilogue rank-2 columns
    float mx0[4], mx1[4];
    #pragma unroll
    for (int j = 0; j < 4; j++) {
        int n = n0 + wc + j * 16 + lrow;
        mx0[j] = Mx[n]; mx1[j] = Mx[N3 + n];
    }

    f32x4 acc[2][4];
    #pragma unroll
    for (int i = 0; i < 2; i++)
        #pragma unroll
        for (int j = 0; j < 4; j++)
            acc[i][j] = (f32x4){0.f, 0.f, 0.f, 0.f};

    for (int kb = 0; kb < S_SZ; kb += 64) {
        __syncthreads();
        #pragma unroll
        for (int c = 0; c < 2; c++) {          // A: 8 chunks, 2 per wave
            int ch = wave * 2 + c;
            int row = ch * 8 + lrow8;
            glds16(&hh[(size_t)(m0 + row) * S_SZ + kb + scolh], &As[ch * 512]);
        }
        #pragma unroll
        for (int c = 0; c < 4; c++) {          // B: 16 chunks, 4 per wave
            int ch = wave * 4 + c;
            int row = ch * 8 + lrow8;
            glds16(&Wt[(size_t)(n0 + row) * S_SZ + kb + scolh], &Bs[ch * 512]);
        }
        __syncthreads();
        #pragma unroll
        for (int kk = 0; kk < 64; kk += 32) {
            f16x8 a[2], b[4];
            #pragma unroll
            for (int i = 0; i < 2; i++)
                a[i] = __builtin_bit_cast(f16x8,
                    *(const u32x4*)&As[(wr + i * 16 + lrow) * 64 +
                                       ((kk + quad * 8) ^ swz)]);
            #pragma unroll
            for (int j = 0; j < 4; j++)
                b[j] = __builtin_bit_cast(f16x8,
                    *(const u32x4*)&Bs[(wc + j * 16 + lrow) * 64 +
                                       ((kk + quad * 8) ^ swz)]);
            #pragma unroll
            for (int i = 0; i < 2; i++)
                #pragma unroll
                for (int j = 0; j < 4; j++)
                    acc[i][j] = __builtin_amdgcn_mfma_f32_16x16x32_f16(
                        a[i], b[j], acc[i][j], 0, 0, 0);
        }
    }

    #pragma unroll
    for (int i = 0; i < 2; i++) {
        #pragma unroll
        for (int rr = 0; rr < 4; rr++) {
            int m = m0 + wr + i * 16 + quad * 4 + rr;
            float a0 = act[((size_t)m * F_SZ + t) * 2 + 0];
            float a1 = act[((size_t)m * F_SZ + t) * 2 + 1];
            #pragma unroll
            for (int j = 0; j < 4; j++) {
                int n = n0 + wc + j * 16 + lrow;
                f16 val = (f16)(acc[i][j][rr] + a0 * mx0[j] + a1 * mx1[j]);
                __builtin_nontemporal_store(val, &parts[(size_t)m * N3 + n]);
            }
        }
    }
}

// ---------------------------------------------------------------------------
// LayerNorm + gates + h update. 2 rows/block; thread owns 8 units.
// parts read non-temporally (no reuse; keep L2 clean for Wt/hh).
__global__ __launch_bounds__(256) void ln_gate_step(
    const f16* __restrict__ parts,
    const float* __restrict__ gamma,
    const float* __restrict__ beta,
    f16* __restrict__ hh,           // fp16 state
    float* __restrict__ hout,       // d_out h region (written only at t=49)
    int t)
{
    const int tid = threadIdx.x;
    const int r2  = tid >> 7;                 // 0..1
    const int tl  = tid & 127;                // owns units tl*8..tl*8+7
    const int row = blockIdx.x * 2 + r2;
    const f16* p = parts + (size_t)row * N3 + tl * 8;

    float v[24];
    float s = 0.f, ss = 0.f;
    #pragma unroll
    for (int g = 0; g < 3; g++) {
        f16x8 x = __builtin_nontemporal_load((const f16x8*)(p + g * S_SZ));
        #pragma unroll
        for (int e = 0; e < 8; e++) {
            float f = (float)x[e];
            v[g * 8 + e] = f;
            s += f; ss += f * f;
        }
    }
    #pragma unroll
    for (int o = 1; o < 64; o <<= 1) {
        s  += __shfl_xor(s, o);
        ss += __shfl_xor(ss, o);
    }
    __shared__ float red[8];
    int wave = tid >> 6, lane = tid & 63;
    if (lane == 0) { red[wave] = s; red[4 + wave] = ss; }
    __syncthreads();
    float S  = red[r2 * 2] + red[r2 * 2 + 1];
    float SS = red[4 + r2 * 2] + red[4 + r2 * 2 + 1];
    float mean = S * (1.f / N3);
    float var  = SS * (1.f / N3) - mean * mean;
    float rstd = rsqrtf(var + 1e-3f);

    float nv[24];
    #pragma unroll
    for (int g = 0; g < 3; g++) {
        f32x4 g0 = *(const f32x4*)(gamma + g * S_SZ + tl * 8);
        f32x4 g1 = *(const f32x4*)(gamma + g * S_SZ + tl * 8 + 4);
        f32x4 b0 = *(const f32x4*)(beta  + g * S_SZ + tl * 8);
        f32x4 b1 = *(const f32x4*)(beta  + g * S_SZ + tl * 8 + 4);
        #pragma unroll
        for (int e = 0; e < 4; e++) {
            nv[g * 8 + e]     = (v[g * 8 + e]     - mean) * rstd * g0[e] + b0[e];
            nv[g * 8 + e + 4] = (v[g * 8 + e + 4] - mean) * rstd * g1[e] + b1[e];
        }
    }

    size_t hbase = (size_t)row * S_SZ + tl * 8;
    f16x8 hp = *(const f16x8*)(hh + hbase);
    f16x8 hs;
    f32x4 ho0, ho1;
    #pragma unroll
    for (int e = 0; e < 8; e++) {
        float rg = 1.f / (1.f + __expf(-nv[e]));
        float x  = rg * nv[8 + e];
        float tt = __expf(-2.f * fabsf(x));            // stable fast tanh
        float cg = __builtin_copysignf((1.f - tt) / (1.f + tt), x);
        float ug = 1.f / (1.f + __expf(-(nv[16 + e] - 1.f)));
        float hv = ug * cg + (1.f - ug) * (float)hp[e];
        hs[e] = (f16)hv;
        if (e < 4) ho0[e] = hv; else ho1[e - 4] = hv;
    }
    *(f16x8*)(hh + hbase) = hs;
    if (t == F_SZ - 1) {
        *(f32x4*)(hout + hbase)     = ho0;
        *(f32x4*)(hout + hbase + 4) = ho1;
    }
}

// ---------------------------------------------------------------------------
// out[B*S + row*2 + {0,1}] = h_row @ W_dec + b_dec   (fp32)
__global__ __launch_bounds__(256) void final_out(
    const float* __restrict__ h, const float* __restrict__ Wd,
    const float* __restrict__ bd, float* __restrict__ out)
{
    int row = blockIdx.x * 4 + (threadIdx.x >> 6);
    int lane = threadIdx.x & 63;
    const float* hr = h + (size_t)row * S_SZ;
    float s0 = 0.f, s1 = 0.f;
    #pragma unroll
    for (int k = lane; k < S_SZ; k += 64) {
        float x = hr[k];
        s0 += x * Wd[k * 2];
        s1 += x * Wd[k * 2 + 1];
    }
    #pragma unroll
    for (int o = 32; o > 0; o >>= 1) {
        s0 += __shfl_down(s0, o);
        s1 += __shfl_down(s1, o);
    }
    if (lane == 0) {
        out[(size_t)B_SZ * S_SZ + row * 2 + 0] = s0 + bd[0];
        out[(size_t)B_SZ * S_SZ + row * 2 + 1] = s1 + bd[1];
    }
}

// ---------------------------------------------------------------------------
extern "C" void kernel_launch(void* const* d_in, const int* in_sizes, int n_in,
                              void* d_out, int out_size, void* d_ws, size_t ws_size,
                              hipStream_t stream)
{
    const float* act = (const float*)d_in[0]; // [2048][50][2]
    const float* We  = (const float*)d_in[1]; // [2][1024]
    const float* Wg  = (const float*)d_in[2]; // [2048][3072]
    const float* lng = (const float*)d_in[3]; // [3072]
    const float* lnb = (const float*)d_in[4]; // [3072]
    const float* Wd  = (const float*)d_in[5]; // [1024][2]
    const float* bd  = (const float*)d_in[6]; // [2]
    float* out = (float*)d_out;               // fp32 [B*S h_last][B*2 outputs]

    char* ws = (char*)d_ws;                   // ws_size = 256 MiB (measured)
    f16*   Wt    = (f16*)ws;                  //  6,291,456 B
    float* Mx    = (float*)(ws + 6291456);    //     24,576 B
    f16*   hh    = (f16*)(ws + 6316032);      //  4,194,304 B fp16 state
    f16*   parts = (f16*)(ws + 10510336);     // 12,582,912 B

    hipMemsetAsync(hh, 0, (size_t)B_SZ * S_SZ * 2, stream);
    hipMemsetAsync(Mx, 0, 2 * N3 * 4, stream);
    make_mx<<<dim3(N3 / 256, 16), 256, 0, stream>>>(We, Wg, Mx);
    transpose_w<<<dim3(N3 / 32, S_SZ / 32), 256, 0, stream>>>(Wg, Wt);

    for (int t = 0; t < F_SZ; t++) {
        gemm_step<<<768, 256, 0, stream>>>(Wt, hh, Mx, act, parts, t);
        ln_gate_step<<<B_SZ / 2, 256, 0, stream>>>(parts, lng, lnb, hh, out, t);
    }
    final_out<<<B_SZ / 4, 256, 0, stream>>>(out, Wd, bd, out);
}